// Round 5
// baseline (134.078 us; speedup 1.0000x reference)
//
#include <hip/hip_runtime.h>
#include <hip/hip_bf16.h>
#include <cstdint>

#define NQ 4096
#define NK 4160        // 4096 pooled spatial + 64 ptr = 130 tiles of 32
#define NSP 16384
#define E 256
#define HD 32
// Q is pre-scaled by SC2E = SCALE*log2e at projection time, so p = exp2(S + c2)
#define SC2E 0.2550348652937f
#define C2_SP  -12.426950408889634f   // (ln4 - 10) * log2e
#define C2_PTR -14.426950408889634f   // (-10) * log2e
#define KSPLIT 4

typedef __attribute__((ext_vector_type(4))) float f32x4;
typedef __attribute__((ext_vector_type(8))) __bf16 bf16x8;
typedef __attribute__((ext_vector_type(4))) __bf16 bf16x4;

// ============ prep: q-split | kv pool+split | weight transpose+split ============
// grid: [0,1024) q bf16, [1024,5184) pool k/v -> bf16, [5184,5440) W^T hi/lo
__global__ __launch_bounds__(256) void prep_kernel(
    const float* __restrict__ q, const float* __restrict__ k, const float* __restrict__ v,
    const float* __restrict__ Wq, const float* __restrict__ Wk,
    const float* __restrict__ Wv, const float* __restrict__ Wo,
    __bf16* __restrict__ qhi, __bf16* __restrict__ khi, __bf16* __restrict__ vhi,
    __bf16* __restrict__ wthi, __bf16* __restrict__ wtlo)
{
  __shared__ float tl[32][33];
  const int b = blockIdx.x, t = threadIdx.x;
  if (b < 1024) {
    const float4 f = *(const float4*)(q + (size_t)b * 1024 + t * 4);
    bf16x4 o;
    o[0] = (__bf16)f.x; o[1] = (__bf16)f.y; o[2] = (__bf16)f.z; o[3] = (__bf16)f.w;
    *(bf16x4*)(qhi + (size_t)b * 1024 + t * 4) = o;
  } else if (b < 5184) {
    const int p = b - 1024;
    float kv, vv;
    if (p < 4096) {
      int f = p >> 10, hp = (p >> 5) & 31, wp = p & 31;
      size_t r0 = (size_t)(f * 4096 + hp * 128 + wp * 2) * E + t;
      kv = 0.25f * (k[r0] + k[r0 + E] + k[r0 + 64 * E] + k[r0 + 65 * E]);
      vv = 0.25f * (v[r0] + v[r0 + E] + v[r0 + 64 * E] + v[r0 + 65 * E]);
    } else {
      size_t r = (size_t)(NSP + (p - 4096)) * E + t;
      kv = k[r]; vv = v[r];
    }
    khi[(size_t)p * E + t] = (__bf16)kv;
    vhi[(size_t)p * E + t] = (__bf16)vv;
  } else {
    const int wb = b - 5184;
    const int wsel = wb >> 6, tile = wb & 63;
    const float* W = (wsel == 0) ? Wq : (wsel == 1) ? Wk : (wsel == 2) ? Wv : Wo;
    __bf16* oh = wthi + (size_t)wsel * 65536;
    __bf16* ol = wtlo + (size_t)wsel * 65536;
    const int tr = (tile >> 3) * 32, tc = (tile & 7) * 32;
    const int rr = t >> 3, cc = (t & 7) * 4;
    *(float4*)&tl[rr][cc] = *(const float4*)(W + (size_t)(tr + rr) * E + tc + cc);
    __syncthreads();
    bf16x4 hv, lv;
#pragma unroll
    for (int i = 0; i < 4; ++i) {
      float x = tl[cc + i][rr];           // W[tr+cc+i][tc+rr]
      __bf16 bh = (__bf16)x;
      hv[i] = bh;
      lv[i] = (__bf16)(x - (float)bh);
    }
    *(bf16x4*)(oh + (size_t)(tc + rr) * E + tr + cc) = hv;
    *(bf16x4*)(ol + (size_t)(tc + rr) * E + tr + cc) = lv;
  }
}

// ============ MFMA GEMM body: Y = X(16 rows,256) @ W(256,256) + b ============
// MODE 0: Q -> bf16 [h][n][32], scaled by SC2E   (X hi, W hi)
// MODE 1: K -> bf16 [h][n][32]                   (X hi, W hi)
// MODE 2: V -> bf16 V^T permuted [h*32+d][NK]    (X hi, W hi, swapped operands)
// MODE 3: O -> f32 row-major [n][256]            (X hi/lo, W hi/lo, 3-mfma)
// block = 256 thr = 4 waves; wave w: cols [64w,64w+64); block rows = 16 at r0.
template<int MODE>
__device__ __forceinline__ void gemm_body(
    const __bf16* __restrict__ X, const __bf16* __restrict__ XL,
    const __bf16* __restrict__ WTH, const __bf16* __restrict__ WTL,
    const float* __restrict__ bias, void* __restrict__ Y, int r0)
{
  const int t = threadIdx.x;
  const int lane = t & 63, ql = lane & 15, g = lane >> 4;
  const int w = t >> 6, c0 = w * 64;

  const __bf16* xp  = X + (size_t)(r0 + ql) * E + g * 8;
  const __bf16* xlp = (MODE == 3) ? XL + (size_t)(r0 + ql) * E + g * 8 : nullptr;
  const __bf16* wh0 = WTH + (size_t)(c0 + ql) * E + g * 8;
  const __bf16* wl0 = (MODE == 3) ? WTL + (size_t)(c0 + ql) * E + g * 8 : nullptr;

  f32x4 acc[4] = {};
#pragma unroll
  for (int k0 = 0; k0 < 8; ++k0) {
    bf16x8 a = *(const bf16x8*)(xp + k0 * 32);
    bf16x8 al{};
    if (MODE == 3) al = *(const bf16x8*)(xlp + k0 * 32);
#pragma unroll
    for (int j = 0; j < 4; ++j) {
      bf16x8 bh = *(const bf16x8*)(wh0 + (size_t)j * 16 * E + k0 * 32);
      if (MODE == 2) {
        acc[j] = __builtin_amdgcn_mfma_f32_16x16x32_bf16(bh, a, acc[j], 0, 0, 0);
      } else {
        acc[j] = __builtin_amdgcn_mfma_f32_16x16x32_bf16(a, bh, acc[j], 0, 0, 0);
        if (MODE == 3) {
          bf16x8 bl = *(const bf16x8*)(wl0 + (size_t)j * 16 * E + k0 * 32);
          acc[j] = __builtin_amdgcn_mfma_f32_16x16x32_bf16(al, bh, acc[j], 0, 0, 0);
          acc[j] = __builtin_amdgcn_mfma_f32_16x16x32_bf16(a, bl, acc[j], 0, 0, 0);
        }
      }
    }
  }

  if (MODE == 0 || MODE == 1) {
    const int NN = (MODE == 0) ? NQ : NK;
#pragma unroll
    for (int j = 0; j < 4; ++j) {
      const int c = c0 + 16 * j + ql;
      const float bv = bias[c];
      const int hh = c >> 5, d = c & 31;
      __bf16* dst = (__bf16*)Y + (size_t)hh * NN * HD + d;
#pragma unroll
      for (int r = 0; r < 4; ++r) {
        const int n = r0 + g * 4 + r;
        float o = acc[j][r] + bv;
        if (MODE == 0) o *= SC2E;
        dst[(size_t)n * HD] = (__bf16)o;
      }
    }
  } else if (MODE == 2) {
    const int n = r0 + ql;
    const int wi = n & 31;
    const int pos = ((wi & 15) >> 2) * 8 + (wi & 3) + 4 * ((wi >> 4) & 1);
    const size_t nb = (size_t)(n >> 5) * 32 + pos;
#pragma unroll
    for (int j = 0; j < 4; ++j)
#pragma unroll
      for (int r = 0; r < 4; ++r) {
        const int ch = c0 + 16 * j + g * 4 + r;
        const int hh = ch >> 5, d = ch & 31;
        ((__bf16*)Y)[(size_t)(hh * HD + d) * NK + nb] = (__bf16)(acc[j][r] + bias[ch]);
      }
  } else {
#pragma unroll
    for (int j = 0; j < 4; ++j) {
      const int c = c0 + 16 * j + ql;
      const float bv = bias[c];
#pragma unroll
      for (int r = 0; r < 4; ++r) {
        const int n = r0 + g * 4 + r;
        ((float*)Y)[(size_t)n * E + c] = acc[j][r] + bv;
      }
    }
  }
}

// fused Q/K/V projection: blocks [0,256) Q, [256,516) K, [516,776) V
__global__ __launch_bounds__(256) void gemm_qkv(
    const __bf16* __restrict__ qhi, const __bf16* __restrict__ khi, const __bf16* __restrict__ vhi,
    const __bf16* __restrict__ wthi, const __bf16* __restrict__ wtlo,
    const float* __restrict__ bq, const float* __restrict__ bk, const float* __restrict__ bv,
    __bf16* __restrict__ qb, __bf16* __restrict__ kb, __bf16* __restrict__ vtp)
{
  const int b = blockIdx.x;
  if (b < 256) {
    gemm_body<0>(qhi, nullptr, wthi, nullptr, bq, qb, b * 16);
  } else if (b < 516) {
    gemm_body<1>(khi, nullptr, wthi + 65536, nullptr, bk, kb, (b - 256) * 16);
  } else {
    gemm_body<2>(vhi, nullptr, wthi + 2 * 65536, nullptr, bv, vtp, (b - 516) * 16);
  }
}

__global__ __launch_bounds__(256) void gemm_o(
    const __bf16* __restrict__ ahi, const __bf16* __restrict__ alo,
    const __bf16* __restrict__ wthi, const __bf16* __restrict__ wtlo,
    const float* __restrict__ bo, float* __restrict__ out)
{
  gemm_body<3>(ahi, alo, wthi, wtlo, bo, out, blockIdx.x * 16);
}

// ============ no-LDS MFMA flash attention ============
// grid 2048 = 256 qtiles x 8 heads (h = blockIdx&7 -> per-XCD L2 K/V residency)
// block 256 = 4 waves; wave w: 16 queries x key-tiles [w*33, w*33+nt) of 32 keys.
// Q pre-scaled by SC2E; c2 folded into QK C-init; lsum via ones-MFMA.
__global__ __launch_bounds__(256) void attn_kernel(
    const __bf16* __restrict__ qb, const __bf16* __restrict__ kb,
    const __bf16* __restrict__ vtp, __bf16* __restrict__ ahi, __bf16* __restrict__ alo)
{
  __shared__ float OUT[KSPLIT][16][32];
  __shared__ float LS[KSPLIT][16];

  const int t = threadIdx.x;
  const int w = t >> 6, lane = t & 63;
  const int ql = lane & 15, g = lane >> 4;
  const int b = blockIdx.x;
  const int h = b & 7, qt = b >> 3;
  const int n0 = qt * 16;

  const bf16x8 bq = *(const bf16x8*)(qb + ((size_t)h * NQ + n0 + ql) * HD + g * 8);

  const int tile0 = w * 33;
  const int nt = (w < 3) ? 33 : 31;          // 33+33+33+31 = 130 tiles
  const __bf16* kp = kb  + ((size_t)h * NK + tile0 * 32 + ql) * HD + g * 8;
  const __bf16* vp = vtp + ((size_t)(h * HD) + ql) * NK + tile0 * 32 + g * 8;  // dims 0-15
  const __bf16* vq = vp + (size_t)16 * NK;                                     // dims 16-31

  f32x4 o0 = {0.f,0.f,0.f,0.f}, o1 = {0.f,0.f,0.f,0.f};
  f32x4 lacc = {0.f,0.f,0.f,0.f};
  bf16x8 ones;
#pragma unroll
  for (int j = 0; j < 8; ++j) ones[j] = (__bf16)1.0f;

  bf16x8 kf0 = *(const bf16x8*)(kp);
  bf16x8 kf1 = *(const bf16x8*)(kp + 512);
  bf16x8 vf0 = *(const bf16x8*)(vp);
  bf16x8 vf1 = *(const bf16x8*)(vq);

#define ABODY(C2V)                                                                \
  {                                                                               \
    f32x4 s0 = __builtin_amdgcn_mfma_f32_16x16x32_bf16(kf0, bq, C2V, 0, 0, 0);    \
    f32x4 s1 = __builtin_amdgcn_mfma_f32_16x16x32_bf16(kf1, bq, C2V, 0, 0, 0);    \
    bf16x8 p;                                                                     \
    _Pragma("unroll")                                                             \
    for (int r = 0; r < 4; ++r) {                                                 \
      p[r]     = (__bf16)exp2f(s0[r]);                                            \
      p[4 + r] = (__bf16)exp2f(s1[r]);                                            \
    }                                                                             \
    o0   = __builtin_amdgcn_mfma_f32_16x16x32_bf16(p, vf0, o0, 0, 0, 0);          \
    o1   = __builtin_amdgcn_mfma_f32_16x16x32_bf16(p, vf1, o1, 0, 0, 0);          \
    lacc = __builtin_amdgcn_mfma_f32_16x16x32_bf16(p, ones, lacc, 0, 0, 0);       \
  }

  for (int it = 0; it < nt - 1; ++it) {
    bf16x8 nk0 = *(const bf16x8*)(kp + (size_t)(it + 1) * 1024);
    bf16x8 nk1 = *(const bf16x8*)(kp + (size_t)(it + 1) * 1024 + 512);
    bf16x8 nv0 = *(const bf16x8*)(vp + (size_t)(it + 1) * 32);
    bf16x8 nv1 = *(const bf16x8*)(vq + (size_t)(it + 1) * 32);
    const float c2 = (tile0 + it < 128) ? C2_SP : C2_PTR;
    const f32x4 c2v = {c2, c2, c2, c2};
    ABODY(c2v)
    kf0 = nk0; kf1 = nk1; vf0 = nv0; vf1 = nv1;
  }
  {
    const float c2 = (tile0 + nt - 1 < 128) ? C2_SP : C2_PTR;
    const f32x4 c2v = {c2, c2, c2, c2};
    ABODY(c2v)
  }
#undef ABODY

#pragma unroll
  for (int r = 0; r < 4; ++r) {
    OUT[w][g * 4 + r][ql]      = o0[r];
    OUT[w][g * 4 + r][16 + ql] = o1[r];
  }
  if (ql == 0) {
#pragma unroll
    for (int r = 0; r < 4; ++r) LS[w][g * 4 + r] = lacc[r];
  }
  __syncthreads();

  if (t < 128) {
    const int q = t >> 3, d0 = (t & 7) * 4;
    f32x4 s = {0.f, 0.f, 0.f, 0.f};
    float ls = 0.f;
#pragma unroll
    for (int w2 = 0; w2 < KSPLIT; ++w2) {
      s  += *(const f32x4*)&OUT[w2][q][d0];
      ls += LS[w2][q];
    }
    const float inv = 1.0f / ls;
    bf16x4 hv, lv;
#pragma unroll
    for (int i = 0; i < 4; ++i) {
      float o = s[i] * inv;
      __bf16 bh = (__bf16)o;
      hv[i] = bh;
      lv[i] = (__bf16)(o - (float)bh);
    }
    const size_t off = (size_t)(n0 + q) * E + h * HD + d0;
    *(bf16x4*)(ahi + off) = hv;
    *(bf16x4*)(alo + off) = lv;
  }
}

extern "C" void kernel_launch(void* const* d_in, const int* in_sizes, int n_in,
                              void* d_out, int out_size, void* d_ws, size_t ws_size,
                              hipStream_t stream)
{
  const float* q  = (const float*)d_in[0];
  const float* k  = (const float*)d_in[1];
  const float* v  = (const float*)d_in[2];
  const float* Wq = (const float*)d_in[3];
  const float* bq = (const float*)d_in[4];
  const float* Wk = (const float*)d_in[5];
  const float* bk = (const float*)d_in[6];
  const float* Wv = (const float*)d_in[7];
  const float* bv = (const float*)d_in[8];
  const float* Wo = (const float*)d_in[9];
  const float* bo = (const float*)d_in[10];
  float* out = (float*)d_out;

  char* wsp = (char*)d_ws;
  __bf16* qhi  = (__bf16*)(wsp);               // 2,097,152
  __bf16* khi  = (__bf16*)(wsp + 2097152);     // 2,129,920
  __bf16* vhi  = (__bf16*)(wsp + 4227072);     // 2,129,920
  __bf16* wthi = (__bf16*)(wsp + 6356992);     //   524,288 (4 x 256x256)
  __bf16* wtlo = (__bf16*)(wsp + 6881280);     //   524,288
  __bf16* qbb  = (__bf16*)(wsp + 7405568);     // 2,097,152
  __bf16* kbb  = (__bf16*)(wsp + 9502720);     // 2,129,920
  __bf16* vtp  = (__bf16*)(wsp + 11632640);    // 2,129,920
  __bf16* ahi  = (__bf16*)(wsp + 13762560);    // 2,097,152
  __bf16* alo  = (__bf16*)(wsp + 15859712);    // 2,097,152 -> end 17,956,864

  prep_kernel<<<5440, 256, 0, stream>>>(q, k, v, Wq, Wk, Wv, Wo, qhi, khi, vhi, wthi, wtlo);
  gemm_qkv<<<776, 256, 0, stream>>>(qhi, khi, vhi, wthi, wtlo, bq, bk, bv, qbb, kbb, vtp);
  attn_kernel<<<2048, 256, 0, stream>>>(qbb, kbb, vtp, ahi, alo);
  gemm_o<<<256, 256, 0, stream>>>(ahi, alo, wthi + 3 * 65536, wtlo + 3 * 65536, bo, out);
}

// Round 6
// 86.009 us; speedup vs baseline: 1.5589x; 1.5589x over previous
//
#include <hip/hip_runtime.h>
#include <hip/hip_bf16.h>
#include <cstdint>

#define NQ 4096
#define NK 4160        // 4096 pooled spatial + 64 ptr = 130 tiles of 32
#define NSP 16384
#define E 256
#define HD 32
// Q is pre-scaled by SC2E = SCALE*log2e at projection time, so p = exp2(S + c2)
#define SC2E 0.2550348652937f
#define C2_SP  -12.426950408889634f   // (ln4 - 10) * log2e
#define C2_PTR -14.426950408889634f   // (-10) * log2e

typedef __attribute__((ext_vector_type(4))) float f32x4;
typedef __attribute__((ext_vector_type(8))) __bf16 bf16x8;
typedef __attribute__((ext_vector_type(4))) __bf16 bf16x4;

// ============ prep: q-split | kv pool+split | weight transpose+split ============
// grid: [0,1024) q bf16, [1024,5184) pool k/v -> bf16, [5184,5440) W^T hi/lo
__global__ __launch_bounds__(256) void prep_kernel(
    const float* __restrict__ q, const float* __restrict__ k, const float* __restrict__ v,
    const float* __restrict__ Wq, const float* __restrict__ Wk,
    const float* __restrict__ Wv, const float* __restrict__ Wo,
    __bf16* __restrict__ qhi, __bf16* __restrict__ khi, __bf16* __restrict__ vhi,
    __bf16* __restrict__ wthi, __bf16* __restrict__ wtlo)
{
  __shared__ float tl[32][33];
  const int b = blockIdx.x, t = threadIdx.x;
  if (b < 1024) {
    const float4 f = *(const float4*)(q + (size_t)b * 1024 + t * 4);
    bf16x4 o;
    o[0] = (__bf16)f.x; o[1] = (__bf16)f.y; o[2] = (__bf16)f.z; o[3] = (__bf16)f.w;
    *(bf16x4*)(qhi + (size_t)b * 1024 + t * 4) = o;
  } else if (b < 5184) {
    const int p = b - 1024;
    float kv, vv;
    if (p < 4096) {
      int f = p >> 10, hp = (p >> 5) & 31, wp = p & 31;
      size_t r0 = (size_t)(f * 4096 + hp * 128 + wp * 2) * E + t;
      kv = 0.25f * (k[r0] + k[r0 + E] + k[r0 + 64 * E] + k[r0 + 65 * E]);
      vv = 0.25f * (v[r0] + v[r0 + E] + v[r0 + 64 * E] + v[r0 + 65 * E]);
    } else {
      size_t r = (size_t)(NSP + (p - 4096)) * E + t;
      kv = k[r]; vv = v[r];
    }
    khi[(size_t)p * E + t] = (__bf16)kv;
    vhi[(size_t)p * E + t] = (__bf16)vv;
  } else {
    const int wb = b - 5184;
    const int wsel = wb >> 6, tile = wb & 63;
    const float* W = (wsel == 0) ? Wq : (wsel == 1) ? Wk : (wsel == 2) ? Wv : Wo;
    __bf16* oh = wthi + (size_t)wsel * 65536;
    __bf16* ol = wtlo + (size_t)wsel * 65536;
    const int tr = (tile >> 3) * 32, tc = (tile & 7) * 32;
    const int rr = t >> 3, cc = (t & 7) * 4;
    *(float4*)&tl[rr][cc] = *(const float4*)(W + (size_t)(tr + rr) * E + tc + cc);
    __syncthreads();
    bf16x4 hv, lv;
#pragma unroll
    for (int i = 0; i < 4; ++i) {
      float x = tl[cc + i][rr];           // W[tr+cc+i][tc+rr]
      __bf16 bh = (__bf16)x;
      hv[i] = bh;
      lv[i] = (__bf16)(x - (float)bh);
    }
    *(bf16x4*)(oh + (size_t)(tc + rr) * E + tr + cc) = hv;
    *(bf16x4*)(ol + (size_t)(tc + rr) * E + tr + cc) = lv;
  }
}

// ============ MFMA GEMM body: Y = X(16 rows,256) @ W(256,256) + b ============
// MODE 0: Q -> bf16 [h][n][32], scaled by SC2E   (X hi, W hi)
// MODE 1: K -> bf16 [h][n][32]                   (X hi, W hi)
// MODE 2: V -> bf16 V^T permuted [h*32+d][NK]    (X hi, W hi, swapped operands)
// MODE 3: O -> f32 row-major [n][256]            (X hi/lo, W hi/lo, 3-mfma)
// block = 256 thr = 4 waves; wave w: cols [64w,64w+64); block rows = 16 at r0.
template<int MODE>
__device__ __forceinline__ void gemm_body(
    const __bf16* __restrict__ X, const __bf16* __restrict__ XL,
    const __bf16* __restrict__ WTH, const __bf16* __restrict__ WTL,
    const float* __restrict__ bias, void* __restrict__ Y, int r0)
{
  const int t = threadIdx.x;
  const int lane = t & 63, ql = lane & 15, g = lane >> 4;
  const int w = t >> 6, c0 = w * 64;

  const __bf16* xp  = X + (size_t)(r0 + ql) * E + g * 8;
  const __bf16* xlp = (MODE == 3) ? XL + (size_t)(r0 + ql) * E + g * 8 : nullptr;
  const __bf16* wh0 = WTH + (size_t)(c0 + ql) * E + g * 8;
  const __bf16* wl0 = (MODE == 3) ? WTL + (size_t)(c0 + ql) * E + g * 8 : nullptr;

  f32x4 acc[4] = {};
#pragma unroll
  for (int k0 = 0; k0 < 8; ++k0) {
    bf16x8 a = *(const bf16x8*)(xp + k0 * 32);
    bf16x8 al{};
    if (MODE == 3) al = *(const bf16x8*)(xlp + k0 * 32);
#pragma unroll
    for (int j = 0; j < 4; ++j) {
      bf16x8 bh = *(const bf16x8*)(wh0 + (size_t)j * 16 * E + k0 * 32);
      if (MODE == 2) {
        acc[j] = __builtin_amdgcn_mfma_f32_16x16x32_bf16(bh, a, acc[j], 0, 0, 0);
      } else {
        acc[j] = __builtin_amdgcn_mfma_f32_16x16x32_bf16(a, bh, acc[j], 0, 0, 0);
        if (MODE == 3) {
          bf16x8 bl = *(const bf16x8*)(wl0 + (size_t)j * 16 * E + k0 * 32);
          acc[j] = __builtin_amdgcn_mfma_f32_16x16x32_bf16(al, bh, acc[j], 0, 0, 0);
          acc[j] = __builtin_amdgcn_mfma_f32_16x16x32_bf16(a, bl, acc[j], 0, 0, 0);
        }
      }
    }
  }

  if (MODE == 0 || MODE == 1) {
    const int NN = (MODE == 0) ? NQ : NK;
#pragma unroll
    for (int j = 0; j < 4; ++j) {
      const int c = c0 + 16 * j + ql;
      const float bv = bias[c];
      const int hh = c >> 5, d = c & 31;
      __bf16* dst = (__bf16*)Y + (size_t)hh * NN * HD + d;
#pragma unroll
      for (int r = 0; r < 4; ++r) {
        const int n = r0 + g * 4 + r;
        float o = acc[j][r] + bv;
        if (MODE == 0) o *= SC2E;
        dst[(size_t)n * HD] = (__bf16)o;
      }
    }
  } else if (MODE == 2) {
    const int n = r0 + ql;
    const int wi = n & 31;
    const int pos = ((wi & 15) >> 2) * 8 + (wi & 3) + 4 * ((wi >> 4) & 1);
    const size_t nb = (size_t)(n >> 5) * 32 + pos;
#pragma unroll
    for (int j = 0; j < 4; ++j)
#pragma unroll
      for (int r = 0; r < 4; ++r) {
        const int ch = c0 + 16 * j + g * 4 + r;
        const int hh = ch >> 5, d = ch & 31;
        ((__bf16*)Y)[(size_t)(hh * HD + d) * NK + nb] = (__bf16)(acc[j][r] + bias[ch]);
      }
  } else {
#pragma unroll
    for (int j = 0; j < 4; ++j) {
      const int c = c0 + 16 * j + ql;
      const float bv = bias[c];
#pragma unroll
      for (int r = 0; r < 4; ++r) {
        const int n = r0 + g * 4 + r;
        ((float*)Y)[(size_t)n * E + c] = acc[j][r] + bv;
      }
    }
  }
}

// fused Q/K/V projection: blocks [0,256) Q, [256,516) K, [516,776) V
__global__ __launch_bounds__(256) void gemm_qkv(
    const __bf16* __restrict__ qhi, const __bf16* __restrict__ khi, const __bf16* __restrict__ vhi,
    const __bf16* __restrict__ wthi, const __bf16* __restrict__ wtlo,
    const float* __restrict__ bq, const float* __restrict__ bk, const float* __restrict__ bv,
    __bf16* __restrict__ qb, __bf16* __restrict__ kb, __bf16* __restrict__ vtp)
{
  const int b = blockIdx.x;
  if (b < 256) {
    gemm_body<0>(qhi, nullptr, wthi, nullptr, bq, qb, b * 16);
  } else if (b < 516) {
    gemm_body<1>(khi, nullptr, wthi + 65536, nullptr, bk, kb, (b - 256) * 16);
  } else {
    gemm_body<2>(vhi, nullptr, wthi + 2 * 65536, nullptr, bv, vtp, (b - 516) * 16);
  }
}

__global__ __launch_bounds__(256) void gemm_o(
    const __bf16* __restrict__ ahi, const __bf16* __restrict__ alo,
    const __bf16* __restrict__ wthi, const __bf16* __restrict__ wtlo,
    const float* __restrict__ bo, float* __restrict__ out)
{
  gemm_body<3>(ahi, alo, wthi, wtlo, bo, out, blockIdx.x * 16);
}

// ============ no-LDS MFMA flash attention, 64q/wave ============
// grid 512 = 64 qtiles x 8 heads (h = blockIdx&7 -> per-XCD L2 K/V residency)
// block 512 = 8 waves; wave w: 64 queries x key-tiles [st, st+nt) of 32 keys
// (tiles 17/17/16x6 = 130). 4 q-frags per wave -> 4 independent QK->exp->PV
// chains per loaded K/V frag. All 4096 waves co-resident (2 blocks/CU).
__global__ __launch_bounds__(512, 4) void attn_kernel(
    const __bf16* __restrict__ qb, const __bf16* __restrict__ kb,
    const __bf16* __restrict__ vtp, __bf16* __restrict__ ahi, __bf16* __restrict__ alo)
{
  __shared__ float OUT[4][64][36];   // pad 36: 16B-aligned f32x4, 2-way banks max
  __shared__ float LS[4][64];

  const int t = threadIdx.x;
  const int w = t >> 6, lane = t & 63;
  const int ql = lane & 15, g = lane >> 4;
  const int b = blockIdx.x;
  const int h = b & 7, qt = b >> 3;
  const int n0 = qt * 64;

  bf16x8 bq[4];
#pragma unroll
  for (int f = 0; f < 4; ++f)
    bq[f] = *(const bf16x8*)(qb + ((size_t)h * NQ + n0 + f * 16 + ql) * HD + g * 8);

  const int st = w * 16 + (w < 2 ? w : 2);   // 0,17,34,50,66,82,98,114
  const int nt = 16 + (w < 2 ? 1 : 0);

  const __bf16* kp = kb  + ((size_t)h * NK + st * 32 + ql) * HD + g * 8;
  const __bf16* vp = vtp + ((size_t)(h * HD) + ql) * NK + st * 32 + g * 8;  // dims 0-15
  const __bf16* vq = vp + (size_t)16 * NK;                                  // dims 16-31

  f32x4 o0[4] = {}, o1[4] = {};
  float ls[4] = {0.f, 0.f, 0.f, 0.f};

  bf16x8 kf0 = *(const bf16x8*)(kp);
  bf16x8 kf1 = *(const bf16x8*)(kp + 512);
  bf16x8 vf0 = *(const bf16x8*)(vp);
  bf16x8 vf1 = *(const bf16x8*)(vq);

#define TILE(C2V)                                                                   \
  _Pragma("unroll")                                                                 \
  for (int f = 0; f < 4; ++f) {                                                     \
    f32x4 s0 = __builtin_amdgcn_mfma_f32_16x16x32_bf16(kf0, bq[f], C2V, 0, 0, 0);   \
    f32x4 s1 = __builtin_amdgcn_mfma_f32_16x16x32_bf16(kf1, bq[f], C2V, 0, 0, 0);   \
    float e0 = exp2f(s0[0]), e1 = exp2f(s0[1]), e2 = exp2f(s0[2]), e3 = exp2f(s0[3]);\
    float e4 = exp2f(s1[0]), e5 = exp2f(s1[1]), e6 = exp2f(s1[2]), e7 = exp2f(s1[3]);\
    ls[f] += ((e0 + e1) + (e2 + e3)) + ((e4 + e5) + (e6 + e7));                     \
    bf16x8 p;                                                                       \
    p[0] = (__bf16)e0; p[1] = (__bf16)e1; p[2] = (__bf16)e2; p[3] = (__bf16)e3;     \
    p[4] = (__bf16)e4; p[5] = (__bf16)e5; p[6] = (__bf16)e6; p[7] = (__bf16)e7;     \
    o0[f] = __builtin_amdgcn_mfma_f32_16x16x32_bf16(p, vf0, o0[f], 0, 0, 0);        \
    o1[f] = __builtin_amdgcn_mfma_f32_16x16x32_bf16(p, vf1, o1[f], 0, 0, 0);        \
  }

  for (int it = 0; it < nt - 1; ++it) {
    bf16x8 nk0 = *(const bf16x8*)(kp + (size_t)(it + 1) * 1024);
    bf16x8 nk1 = *(const bf16x8*)(kp + (size_t)(it + 1) * 1024 + 512);
    bf16x8 nv0 = *(const bf16x8*)(vp + (size_t)(it + 1) * 32);
    bf16x8 nv1 = *(const bf16x8*)(vq + (size_t)(it + 1) * 32);
    const float c2 = (st + it < 128) ? C2_SP : C2_PTR;
    const f32x4 c2v = {c2, c2, c2, c2};
    TILE(c2v)
    kf0 = nk0; kf1 = nk1; vf0 = nv0; vf1 = nv1;
  }
  {
    const float c2 = (st + nt - 1 < 128) ? C2_SP : C2_PTR;
    const f32x4 c2v = {c2, c2, c2, c2};
    TILE(c2v)
  }
#undef TILE

#pragma unroll
  for (int f = 0; f < 4; ++f) {
    ls[f] += __shfl_xor(ls[f], 16);
    ls[f] += __shfl_xor(ls[f], 32);
  }

  // two-phase partial merge: waves 0-3 write, waves 4-7 add
  if (w < 4) {
#pragma unroll
    for (int f = 0; f < 4; ++f) {
#pragma unroll
      for (int r = 0; r < 4; ++r) {
        OUT[w][f * 16 + g * 4 + r][ql]      = o0[f][r];
        OUT[w][f * 16 + g * 4 + r][16 + ql] = o1[f][r];
      }
      if (g == 0) LS[w][f * 16 + ql] = ls[f];
    }
  }
  __syncthreads();
  if (w >= 4) {
    const int w4 = w - 4;
#pragma unroll
    for (int f = 0; f < 4; ++f) {
#pragma unroll
      for (int r = 0; r < 4; ++r) {
        OUT[w4][f * 16 + g * 4 + r][ql]      += o0[f][r];
        OUT[w4][f * 16 + g * 4 + r][16 + ql] += o1[f][r];
      }
      if (g == 0) LS[w4][f * 16 + ql] += ls[f];
    }
  }
  __syncthreads();

  {
    const int q = t >> 3, d0 = (t & 7) * 4;
    f32x4 s = *(const f32x4*)&OUT[0][q][d0];
    float lsum = LS[0][q];
#pragma unroll
    for (int w2 = 1; w2 < 4; ++w2) {
      s += *(const f32x4*)&OUT[w2][q][d0];
      lsum += LS[w2][q];
    }
    const float inv = 1.0f / lsum;
    bf16x4 hv, lv;
#pragma unroll
    for (int i = 0; i < 4; ++i) {
      float o = s[i] * inv;
      __bf16 bh = (__bf16)o;
      hv[i] = bh;
      lv[i] = (__bf16)(o - (float)bh);
    }
    const size_t off = (size_t)(n0 + q) * E + h * HD + d0;
    *(bf16x4*)(ahi + off) = hv;
    *(bf16x4*)(alo + off) = lv;
  }
}

extern "C" void kernel_launch(void* const* d_in, const int* in_sizes, int n_in,
                              void* d_out, int out_size, void* d_ws, size_t ws_size,
                              hipStream_t stream)
{
  const float* q  = (const float*)d_in[0];
  const float* k  = (const float*)d_in[1];
  const float* v  = (const float*)d_in[2];
  const float* Wq = (const float*)d_in[3];
  const float* bq = (const float*)d_in[4];
  const float* Wk = (const float*)d_in[5];
  const float* bk = (const float*)d_in[6];
  const float* Wv = (const float*)d_in[7];
  const float* bv = (const float*)d_in[8];
  const float* Wo = (const float*)d_in[9];
  const float* bo = (const float*)d_in[10];
  float* out = (float*)d_out;

  char* wsp = (char*)d_ws;
  __bf16* qhi  = (__bf16*)(wsp);               // 2,097,152
  __bf16* khi  = (__bf16*)(wsp + 2097152);     // 2,129,920
  __bf16* vhi  = (__bf16*)(wsp + 4227072);     // 2,129,920
  __bf16* wthi = (__bf16*)(wsp + 6356992);     //   524,288 (4 x 256x256)
  __bf16* wtlo = (__bf16*)(wsp + 6881280);     //   524,288
  __bf16* qbb  = (__bf16*)(wsp + 7405568);     // 2,097,152
  __bf16* kbb  = (__bf16*)(wsp + 9502720);     // 2,129,920
  __bf16* vtp  = (__bf16*)(wsp + 11632640);    // 2,129,920
  __bf16* ahi  = (__bf16*)(wsp + 13762560);    // 2,097,152
  __bf16* alo  = (__bf16*)(wsp + 15859712);    // 2,097,152 -> end 17,956,864

  prep_kernel<<<5440, 256, 0, stream>>>(q, k, v, Wq, Wk, Wv, Wo, qhi, khi, vhi, wthi, wtlo);
  gemm_qkv<<<776, 256, 0, stream>>>(qhi, khi, vhi, wthi, wtlo, bq, bk, bv, qbb, kbb, vtp);
  attn_kernel<<<512, 512, 0, stream>>>(qbb, kbb, vtp, ahi, alo);
  gemm_o<<<256, 256, 0, stream>>>(ahi, alo, wthi + 3 * 65536, wtlo + 3 * 65536, bo, out);
}

// Round 7
// 69.979 us; speedup vs baseline: 1.9160x; 1.2291x over previous
//
#include <hip/hip_runtime.h>
#include <hip/hip_bf16.h>
#include <cstdint>

#define NQ 4096
#define NK 4160        // 4096 pooled spatial + 64 ptr = 130 tiles of 32
#define NSP 16384
#define E 256
#define HD 32
// Q is pre-scaled by SC2E = SCALE*log2e at projection time, so p = exp2(S + c2)
#define SC2E 0.2550348652937f
#define C2_SP  -12.426950408889634f   // (ln4 - 10) * log2e
#define C2_PTR -14.426950408889634f   // (-10) * log2e

typedef __attribute__((ext_vector_type(4))) float f32x4;
typedef __attribute__((ext_vector_type(8))) __bf16 bf16x8;
typedef __attribute__((ext_vector_type(4))) __bf16 bf16x4;

// ============ weights prep: W^T hi/lo (4 x 256x256) ============
__global__ __launch_bounds__(256) void wprep_kernel(
    const float* __restrict__ Wq, const float* __restrict__ Wk,
    const float* __restrict__ Wv, const float* __restrict__ Wo,
    __bf16* __restrict__ wthi, __bf16* __restrict__ wtlo)
{
  __shared__ float tl[32][33];
  const int b = blockIdx.x, t = threadIdx.x;
  const int wsel = b >> 6, tile = b & 63;
  const float* W = (wsel == 0) ? Wq : (wsel == 1) ? Wk : (wsel == 2) ? Wv : Wo;
  __bf16* oh = wthi + (size_t)wsel * 65536;
  __bf16* ol = wtlo + (size_t)wsel * 65536;
  const int tr = (tile >> 3) * 32, tc = (tile & 7) * 32;
  const int rr = t >> 3, cc = (t & 7) * 4;
  *(float4*)&tl[rr][cc] = *(const float4*)(W + (size_t)(tr + rr) * E + tc + cc);
  __syncthreads();
  bf16x4 hv, lv;
#pragma unroll
  for (int i = 0; i < 4; ++i) {
    float x = tl[cc + i][rr];           // W[tr+cc+i][tc+rr]
    __bf16 bh = (__bf16)x;
    hv[i] = bh;
    lv[i] = (__bf16)(x - (float)bh);
  }
  *(bf16x4*)(oh + (size_t)(tc + rr) * E + tr + cc) = hv;
  *(bf16x4*)(ol + (size_t)(tc + rr) * E + tr + cc) = lv;
}

// ============ fused stage(+pool)+MFMA projection: 16 rows x 256 cols per block ============
// MODE 0: Q (f32 in) -> bf16 [h][n][32], scaled by SC2E
// MODE 1: K (f32 in, pooled) -> bf16 [h][n][32]
// MODE 2: V (f32 in, pooled) -> bf16 V^T permuted [h*32+d][NK] (swapped operands)
template<int MODE>
__device__ __forceinline__ void qkv_body(
    const float* __restrict__ Xsrc, const __bf16* __restrict__ WTH,
    const float* __restrict__ bias, void* __restrict__ Y, int r0)
{
  __shared__ __bf16 Xs[16][264];   // pad 264: <=2-way banks on b128 frag reads
  const int t = threadIdx.x;

  // ---- stage: pool (K/V) or copy (Q), f32 -> bf16, into LDS ----
  {
    const int pr = t >> 4, f4 = t & 15;   // pooled row, float4-chunk
    const int p = r0 + pr;
    float4 x[4];
    if (MODE == 0) {
      const float* src = Xsrc + (size_t)p * E + f4 * 4;
#pragma unroll
      for (int j = 0; j < 4; ++j) x[j] = *(const float4*)(src + j * 64);
    } else if (p < 4096) {
      const int fr = p >> 10, hp = (p >> 5) & 31, wp = p & 31;
      const float* src = Xsrc + (size_t)(fr * 4096 + hp * 128 + wp * 2) * E + f4 * 4;
#pragma unroll
      for (int j = 0; j < 4; ++j) {
        float4 a = *(const float4*)(src + j * 64);
        float4 b = *(const float4*)(src + j * 64 + E);
        float4 c = *(const float4*)(src + j * 64 + 64 * E);
        float4 d = *(const float4*)(src + j * 64 + 65 * E);
        x[j].x = 0.25f * (a.x + b.x + c.x + d.x);
        x[j].y = 0.25f * (a.y + b.y + c.y + d.y);
        x[j].z = 0.25f * (a.z + b.z + c.z + d.z);
        x[j].w = 0.25f * (a.w + b.w + c.w + d.w);
      }
    } else {
      const float* src = Xsrc + (size_t)(NSP + p - 4096) * E + f4 * 4;
#pragma unroll
      for (int j = 0; j < 4; ++j) x[j] = *(const float4*)(src + j * 64);
    }
#pragma unroll
    for (int j = 0; j < 4; ++j) {
      bf16x4 o;
      o[0] = (__bf16)x[j].x; o[1] = (__bf16)x[j].y;
      o[2] = (__bf16)x[j].z; o[3] = (__bf16)x[j].w;
      *(bf16x4*)&Xs[pr][f4 * 4 + j * 64] = o;
    }
  }
  __syncthreads();

  // ---- compute ----
  const int lane = t & 63, ql = lane & 15, g = lane >> 4;
  const int w = t >> 6, c0 = w * 64;
  const __bf16* wh0 = WTH + (size_t)(c0 + ql) * E + g * 8;

  f32x4 acc[4] = {};
#pragma unroll
  for (int k0 = 0; k0 < 8; ++k0) {
    bf16x8 a = *(const bf16x8*)&Xs[ql][g * 8 + k0 * 32];
#pragma unroll
    for (int j = 0; j < 4; ++j) {
      bf16x8 bh = *(const bf16x8*)(wh0 + (size_t)j * 16 * E + k0 * 32);
      if (MODE == 2) acc[j] = __builtin_amdgcn_mfma_f32_16x16x32_bf16(bh, a, acc[j], 0, 0, 0);
      else           acc[j] = __builtin_amdgcn_mfma_f32_16x16x32_bf16(a, bh, acc[j], 0, 0, 0);
    }
  }

  if (MODE == 0 || MODE == 1) {
    const int NN = (MODE == 0) ? NQ : NK;
#pragma unroll
    for (int j = 0; j < 4; ++j) {
      const int c = c0 + 16 * j + ql;
      const float bv = bias[c];
      const int hh = c >> 5, d = c & 31;
      __bf16* dst = (__bf16*)Y + (size_t)hh * NN * HD + d;
#pragma unroll
      for (int r = 0; r < 4; ++r) {
        const int n = r0 + g * 4 + r;
        float o = acc[j][r] + bv;
        if (MODE == 0) o *= SC2E;
        dst[(size_t)n * HD] = (__bf16)o;
      }
    }
  } else {
    const int n = r0 + ql;
    const int wi = n & 31;
    const int pos = ((wi & 15) >> 2) * 8 + (wi & 3) + 4 * ((wi >> 4) & 1);
    const size_t nb = (size_t)(n >> 5) * 32 + pos;
#pragma unroll
    for (int j = 0; j < 4; ++j)
#pragma unroll
      for (int r = 0; r < 4; ++r) {
        const int ch = c0 + 16 * j + g * 4 + r;
        const int hh = ch >> 5, d = ch & 31;
        ((__bf16*)Y)[(size_t)(hh * HD + d) * NK + nb] = (__bf16)(acc[j][r] + bias[ch]);
      }
  }
}

// fused Q/K/V projection: blocks [0,256) Q, [256,516) K, [516,776) V
__global__ __launch_bounds__(256) void gemm_qkv(
    const float* __restrict__ q, const float* __restrict__ k, const float* __restrict__ v,
    const __bf16* __restrict__ wthi,
    const float* __restrict__ bq, const float* __restrict__ bk, const float* __restrict__ bv,
    __bf16* __restrict__ qb, __bf16* __restrict__ kb, __bf16* __restrict__ vtp)
{
  const int b = blockIdx.x;
  if (b < 256) {
    qkv_body<0>(q, wthi, bq, qb, b * 16);
  } else if (b < 516) {
    qkv_body<1>(k, wthi + 65536, bk, kb, (b - 256) * 16);
  } else {
    qkv_body<2>(v, wthi + 2 * 65536, bv, vtp, (b - 516) * 16);
  }
}

// ============ O-GEMM: out = [ahi+alo](N,256) @ Wo(256,256) + bo, 3-mfma hi/lo ============
__global__ __launch_bounds__(256) void gemm_o(
    const __bf16* __restrict__ ahi, const __bf16* __restrict__ alo,
    const __bf16* __restrict__ WTH, const __bf16* __restrict__ WTL,
    const float* __restrict__ bias, float* __restrict__ out)
{
  const int r0 = blockIdx.x * 16;
  const int t = threadIdx.x;
  const int lane = t & 63, ql = lane & 15, g = lane >> 4;
  const int w = t >> 6, c0 = w * 64;

  const __bf16* xp  = ahi + (size_t)(r0 + ql) * E + g * 8;
  const __bf16* xlp = alo + (size_t)(r0 + ql) * E + g * 8;
  const __bf16* wh0 = WTH + (size_t)(c0 + ql) * E + g * 8;
  const __bf16* wl0 = WTL + (size_t)(c0 + ql) * E + g * 8;

  f32x4 acc[4] = {};
#pragma unroll
  for (int k0 = 0; k0 < 8; ++k0) {
    bf16x8 a  = *(const bf16x8*)(xp + k0 * 32);
    bf16x8 al = *(const bf16x8*)(xlp + k0 * 32);
#pragma unroll
    for (int j = 0; j < 4; ++j) {
      bf16x8 bh = *(const bf16x8*)(wh0 + (size_t)j * 16 * E + k0 * 32);
      bf16x8 bl = *(const bf16x8*)(wl0 + (size_t)j * 16 * E + k0 * 32);
      acc[j] = __builtin_amdgcn_mfma_f32_16x16x32_bf16(a,  bh, acc[j], 0, 0, 0);
      acc[j] = __builtin_amdgcn_mfma_f32_16x16x32_bf16(al, bh, acc[j], 0, 0, 0);
      acc[j] = __builtin_amdgcn_mfma_f32_16x16x32_bf16(a,  bl, acc[j], 0, 0, 0);
    }
  }
#pragma unroll
  for (int j = 0; j < 4; ++j) {
    const int c = c0 + 16 * j + ql;
    const float bv = bias[c];
#pragma unroll
    for (int r = 0; r < 4; ++r) {
      const int n = r0 + g * 4 + r;
      out[(size_t)n * E + c] = acc[j][r] + bv;
    }
  }
}

// ============ no-LDS MFMA flash attention, 64q/wave ============
// grid 512 = 64 qtiles x 8 heads (h = blockIdx&7 -> per-XCD L2 K/V residency)
// block 512 = 8 waves; wave w: 64 queries x key-tiles [st, st+nt) of 32 keys
// (tiles 17/17/16x6 = 130). 4 q-frags per wave. Raw v_exp_f32 via builtin
// (args in [-17,-9] -> outputs normal; OCML denorm fixup unnecessary).
__global__ __launch_bounds__(512, 4) void attn_kernel(
    const __bf16* __restrict__ qb, const __bf16* __restrict__ kb,
    const __bf16* __restrict__ vtp, __bf16* __restrict__ ahi, __bf16* __restrict__ alo)
{
  __shared__ float OUT[4][64][36];   // pad 36: 16B-aligned f32x4, 2-way banks max
  __shared__ float LS[4][64];

  const int t = threadIdx.x;
  const int w = t >> 6, lane = t & 63;
  const int ql = lane & 15, g = lane >> 4;
  const int b = blockIdx.x;
  const int h = b & 7, qt = b >> 3;
  const int n0 = qt * 64;

  bf16x8 bq[4];
#pragma unroll
  for (int f = 0; f < 4; ++f)
    bq[f] = *(const bf16x8*)(qb + ((size_t)h * NQ + n0 + f * 16 + ql) * HD + g * 8);

  const int st = w * 16 + (w < 2 ? w : 2);   // 0,17,34,50,66,82,98,114
  const int nt = 16 + (w < 2 ? 1 : 0);

  const __bf16* kp = kb  + ((size_t)h * NK + st * 32 + ql) * HD + g * 8;
  const __bf16* vp = vtp + ((size_t)(h * HD) + ql) * NK + st * 32 + g * 8;  // dims 0-15
  const __bf16* vq = vp + (size_t)16 * NK;                                  // dims 16-31

  f32x4 o0[4] = {}, o1[4] = {};
  float ls[4] = {0.f, 0.f, 0.f, 0.f};

  bf16x8 kf0 = *(const bf16x8*)(kp);
  bf16x8 kf1 = *(const bf16x8*)(kp + 512);
  bf16x8 vf0 = *(const bf16x8*)(vp);
  bf16x8 vf1 = *(const bf16x8*)(vq);

#define TILE(C2V)                                                                   \
  _Pragma("unroll")                                                                 \
  for (int f = 0; f < 4; ++f) {                                                     \
    f32x4 s0 = __builtin_amdgcn_mfma_f32_16x16x32_bf16(kf0, bq[f], C2V, 0, 0, 0);   \
    f32x4 s1 = __builtin_amdgcn_mfma_f32_16x16x32_bf16(kf1, bq[f], C2V, 0, 0, 0);   \
    float e0 = __builtin_amdgcn_exp2f(s0[0]), e1 = __builtin_amdgcn_exp2f(s0[1]);   \
    float e2 = __builtin_amdgcn_exp2f(s0[2]), e3 = __builtin_amdgcn_exp2f(s0[3]);   \
    float e4 = __builtin_amdgcn_exp2f(s1[0]), e5 = __builtin_amdgcn_exp2f(s1[1]);   \
    float e6 = __builtin_amdgcn_exp2f(s1[2]), e7 = __builtin_amdgcn_exp2f(s1[3]);   \
    ls[f] += ((e0 + e1) + (e2 + e3)) + ((e4 + e5) + (e6 + e7));                     \
    bf16x8 p;                                                                       \
    p[0] = (__bf16)e0; p[1] = (__bf16)e1; p[2] = (__bf16)e2; p[3] = (__bf16)e3;     \
    p[4] = (__bf16)e4; p[5] = (__bf16)e5; p[6] = (__bf16)e6; p[7] = (__bf16)e7;     \
    o0[f] = __builtin_amdgcn_mfma_f32_16x16x32_bf16(p, vf0, o0[f], 0, 0, 0);        \
    o1[f] = __builtin_amdgcn_mfma_f32_16x16x32_bf16(p, vf1, o1[f], 0, 0, 0);        \
  }

  for (int it = 0; it < nt - 1; ++it) {
    bf16x8 nk0 = *(const bf16x8*)(kp + (size_t)(it + 1) * 1024);
    bf16x8 nk1 = *(const bf16x8*)(kp + (size_t)(it + 1) * 1024 + 512);
    bf16x8 nv0 = *(const bf16x8*)(vp + (size_t)(it + 1) * 32);
    bf16x8 nv1 = *(const bf16x8*)(vq + (size_t)(it + 1) * 32);
    const float c2 = (st + it < 128) ? C2_SP : C2_PTR;
    const f32x4 c2v = {c2, c2, c2, c2};
    TILE(c2v)
    kf0 = nk0; kf1 = nk1; vf0 = nv0; vf1 = nv1;
  }
  {
    const float c2 = (st + nt - 1 < 128) ? C2_SP : C2_PTR;
    const f32x4 c2v = {c2, c2, c2, c2};
    TILE(c2v)
  }
#undef TILE

#pragma unroll
  for (int f = 0; f < 4; ++f) {
    ls[f] += __shfl_xor(ls[f], 16);
    ls[f] += __shfl_xor(ls[f], 32);
  }

  // two-phase partial merge: waves 0-3 write, waves 4-7 add
  if (w < 4) {
#pragma unroll
    for (int f = 0; f < 4; ++f) {
#pragma unroll
      for (int r = 0; r < 4; ++r) {
        OUT[w][f * 16 + g * 4 + r][ql]      = o0[f][r];
        OUT[w][f * 16 + g * 4 + r][16 + ql] = o1[f][r];
      }
      if (g == 0) LS[w][f * 16 + ql] = ls[f];
    }
  }
  __syncthreads();
  if (w >= 4) {
    const int w4 = w - 4;
#pragma unroll
    for (int f = 0; f < 4; ++f) {
#pragma unroll
      for (int r = 0; r < 4; ++r) {
        OUT[w4][f * 16 + g * 4 + r][ql]      += o0[f][r];
        OUT[w4][f * 16 + g * 4 + r][16 + ql] += o1[f][r];
      }
      if (g == 0) LS[w4][f * 16 + ql] += ls[f];
    }
  }
  __syncthreads();

  {
    const int q = t >> 3, d0 = (t & 7) * 4;
    f32x4 s = *(const f32x4*)&OUT[0][q][d0];
    float lsum = LS[0][q];
#pragma unroll
    for (int w2 = 1; w2 < 4; ++w2) {
      s += *(const f32x4*)&OUT[w2][q][d0];
      lsum += LS[w2][q];
    }
    const float inv = 1.0f / lsum;
    bf16x4 hv, lv;
#pragma unroll
    for (int i = 0; i < 4; ++i) {
      float o = s[i] * inv;
      __bf16 bh = (__bf16)o;
      hv[i] = bh;
      lv[i] = (__bf16)(o - (float)bh);
    }
    const size_t off = (size_t)(n0 + q) * E + h * HD + d0;
    *(bf16x4*)(ahi + off) = hv;
    *(bf16x4*)(alo + off) = lv;
  }
}

extern "C" void kernel_launch(void* const* d_in, const int* in_sizes, int n_in,
                              void* d_out, int out_size, void* d_ws, size_t ws_size,
                              hipStream_t stream)
{
  const float* q  = (const float*)d_in[0];
  const float* k  = (const float*)d_in[1];
  const float* v  = (const float*)d_in[2];
  const float* Wq = (const float*)d_in[3];
  const float* bq = (const float*)d_in[4];
  const float* Wk = (const float*)d_in[5];
  const float* bk = (const float*)d_in[6];
  const float* Wv = (const float*)d_in[7];
  const float* bv = (const float*)d_in[8];
  const float* Wo = (const float*)d_in[9];
  const float* bo = (const float*)d_in[10];
  float* out = (float*)d_out;

  char* wsp = (char*)d_ws;
  __bf16* wthi = (__bf16*)(wsp);               //   524,288 (4 x 256x256)
  __bf16* wtlo = (__bf16*)(wsp + 524288);      //   524,288
  __bf16* qbb  = (__bf16*)(wsp + 1048576);     // 2,097,152
  __bf16* kbb  = (__bf16*)(wsp + 3145728);     // 2,129,920
  __bf16* vtp  = (__bf16*)(wsp + 5275648);     // 2,129,920
  __bf16* ahi  = (__bf16*)(wsp + 7405568);     // 2,097,152
  __bf16* alo  = (__bf16*)(wsp + 9502720);     // 2,097,152 -> end 11,599,872

  wprep_kernel<<<256, 256, 0, stream>>>(Wq, Wk, Wv, Wo, wthi, wtlo);
  gemm_qkv<<<776, 256, 0, stream>>>(q, k, v, wthi, bq, bk, bv, qbb, kbb, vtp);
  attn_kernel<<<512, 512, 0, stream>>>(qbb, kbb, vtp, ahi, alo);
  gemm_o<<<256, 256, 0, stream>>>(ahi, alo, wthi + 3 * 65536, wtlo + 3 * 65536, bo, out);
}